// Round 1
// baseline (150.112 us; speedup 1.0000x reference)
//
#include <hip/hip_runtime.h>
#include <math.h>

// TopKRouter: x (16384 x 2048) @ gate_w^T (2048 x 64) -> logits (16384 x 64)
// -> top-2 (desc, ties -> lower index) -> softmax over the 2 values.
// Output (float32 buffer): [indices as floats (N*2)] ++ [weights (N*2)].

constexpr int D_DIM = 2048;
constexpr int E_DIM = 64;    // experts (== output N of the skinny GEMM)
constexpr int BM    = 64;    // rows per block
constexpr int BK    = 64;    // K-chunk
constexpr int PADS  = BM + 4; // padded LDS stride (68 floats = 272 B, 16B-aligned rows)

__global__ __launch_bounds__(256, 1)
void router_gemm_topk(const float* __restrict__ x,
                      const float* __restrict__ w,
                      float* __restrict__ out,
                      int nrows) {
    // Transposed tiles: xT[k][r], wT[k][e]; stride PADS avoids bank conflicts
    // and keeps float4 rows 16B-aligned (272 = 17*16).
    __shared__ alignas(16) float xT[BK * PADS];
    __shared__ alignas(16) float wT[BK * PADS];

    const int t   = threadIdx.x;
    const int tx  = t & 15;   // expert group: experts [4*tx, 4*tx+4)
    const int ty  = t >> 4;   // row group:    rows    [4*ty, 4*ty+4)
    const int row0 = blockIdx.x * BM;

    float acc[4][4] = {};

    for (int k0 = 0; k0 < D_DIM; k0 += BK) {
        // ---- stage: BM x BK of x and E x BK of w, transposed into LDS ----
        // 1024 float4 loads per tile, 256 threads -> 4 each; lanes 0..15 read
        // 256 contiguous bytes of one row (coalesced).
        #pragma unroll
        for (int i = 0; i < 4; ++i) {
            const int id = t + i * 256;     // 0..1023
            const int r  = id >> 4;         // row (x) / expert (w): 0..63
            const int kc = id & 15;         // float4 index along K
            const float4 vx = *reinterpret_cast<const float4*>(
                &x[(long)(row0 + r) * D_DIM + k0 + kc * 4]);
            const float4 vw = *reinterpret_cast<const float4*>(
                &w[(long)r * D_DIM + k0 + kc * 4]);
            const int kb = kc * 4;
            xT[(kb + 0) * PADS + r] = vx.x;
            xT[(kb + 1) * PADS + r] = vx.y;
            xT[(kb + 2) * PADS + r] = vx.z;
            xT[(kb + 3) * PADS + r] = vx.w;
            wT[(kb + 0) * PADS + r] = vw.x;
            wT[(kb + 1) * PADS + r] = vw.y;
            wT[(kb + 2) * PADS + r] = vw.z;
            wT[(kb + 3) * PADS + r] = vw.w;
        }
        __syncthreads();

        // ---- compute: 16 FMAs per kk per thread, 2x ds_read_b128 ----
        #pragma unroll 16
        for (int kk = 0; kk < BK; ++kk) {
            const float4 a = *reinterpret_cast<const float4*>(&xT[kk * PADS + ty * 4]);
            const float4 b = *reinterpret_cast<const float4*>(&wT[kk * PADS + tx * 4]);
            acc[0][0] += a.x * b.x; acc[0][1] += a.x * b.y; acc[0][2] += a.x * b.z; acc[0][3] += a.x * b.w;
            acc[1][0] += a.y * b.x; acc[1][1] += a.y * b.y; acc[1][2] += a.y * b.z; acc[1][3] += a.y * b.w;
            acc[2][0] += a.z * b.x; acc[2][1] += a.z * b.y; acc[2][2] += a.z * b.z; acc[2][3] += a.z * b.w;
            acc[3][0] += a.w * b.x; acc[3][1] += a.w * b.y; acc[3][2] += a.w * b.z; acc[3][3] += a.w * b.w;
        }
        __syncthreads();
    }

    // ---- epilogue: logits -> LDS (reuse xT), then per-row top-2 + softmax ----
    #pragma unroll
    for (int i = 0; i < 4; ++i)
        #pragma unroll
        for (int j = 0; j < 4; ++j)
            xT[(ty * 4 + i) * PADS + tx * 4 + j] = acc[i][j];
    __syncthreads();

    if (t < BM) {
        const float* lg = &xT[t * PADS];
        float m1 = lg[0]; int i1 = 0;
        float m2 = -INFINITY; int i2 = 0;
        #pragma unroll
        for (int e = 1; e < E_DIM; ++e) {
            const float v = lg[e];
            if (v > m1)      { m2 = m1; i2 = i1; m1 = v; i1 = e; }
            else if (v > m2) { m2 = v;  i2 = e; }
        }
        // softmax over [m1, m2] (descending order, matching lax.top_k)
        const float e2 = expf(m2 - m1);
        const float s  = 1.0f + e2;
        const long  r  = row0 + t;
        const long  off = (long)nrows * 2;
        out[2 * r + 0]       = (float)i1;
        out[2 * r + 1]       = (float)i2;
        out[off + 2 * r + 0] = 1.0f / s;
        out[off + 2 * r + 1] = e2 / s;
    }
}

extern "C" void kernel_launch(void* const* d_in, const int* in_sizes, int n_in,
                              void* d_out, int out_size, void* d_ws, size_t ws_size,
                              hipStream_t stream) {
    const float* x = (const float*)d_in[0];
    const float* w = (const float*)d_in[1];
    float* out = (float*)d_out;
    const int nrows = in_sizes[0] / D_DIM;   // 16384
    const int grid  = nrows / BM;            // 256
    hipLaunchKernelGGL(router_gemm_topk, dim3(grid), dim3(256), 0, stream,
                       x, w, out, nrows);
}